// Round 6
// baseline (315.525 us; speedup 1.0000x reference)
//
#include <hip/hip_runtime.h>

#define DIM 192
#define DD  (DIM * DIM)
#define DDD (DIM * DIM * DIM)
#define INV27 (1.0f / 27.0f)
#define EPS 1e-5f

#define TY 12         // output rows per block
#define ZC 12         // output planes per block
#define NRS (TY + 4)  // 16 rowsum slots  (rows y0-2 .. y0+13, clamped)
#define NPR (TY + 2)  // 14 product slots (rows y0-1 .. y0+12, clamped)

// grid = (192/ZC=16, 192/TY=16, 2) = 512 blocks of 512 thr = exactly 2/CU

__device__ __forceinline__ int iclamp(int v, int hi) {
    return v < 0 ? 0 : (v > hi ? hi : v);
}

// x-direction 3-tap sliding sum across the wave (lane t owns x=3t..3t+2),
// replicate at x=0 / x=191.
__device__ __forceinline__ float3 xrowsum(float v0, float v1, float v2, int t) {
    float L = __shfl(v2, t - 1); L = (t == 0)  ? v0 : L;
    float R = __shfl(v0, t + 1); R = (t == 63) ? v2 : R;
    return make_float3(L + v0 + v1, v0 + v1 + v2, v1 + v2 + R);
}

// push y-window (3 rowsum rows) into a 3-deep z-ring
__device__ __forceinline__ void ringpush(float r[3][3], const float RS[][DIM],
                                         int sm_, int sc_, int sp_, int x) {
    float3 q0 = *(const float3*)&RS[sm_][x];
    float3 q1 = *(const float3*)&RS[sc_][x];
    float3 q2 = *(const float3*)&RS[sp_][x];
    r[0][0] = r[1][0]; r[0][1] = r[1][1]; r[0][2] = r[1][2];
    r[1][0] = r[2][0]; r[1][1] = r[2][1]; r[1][2] = r[2][2];
    r[2][0] = q0.x + q1.x + q2.x;
    r[2][1] = q0.y + q1.y + q2.y;
    r[2][2] = q0.z + q1.z + q2.z;
}

// dF/dM -> 3 products -> x-rowsums -> PRS row tt
__device__ __forceinline__ void products(const float rf[3][3], const float rm[3][3],
                                         float cf0, float cf1, float cf2,
                                         float cm0, float cm1, float cm2,
                                         int t, int tt, int x,
                                         float P[3][NPR][DIM]) {
    float uf0 = (rf[0][0] + rf[1][0] + rf[2][0]) * INV27;
    float uf1 = (rf[0][1] + rf[1][1] + rf[2][1]) * INV27;
    float uf2 = (rf[0][2] + rf[1][2] + rf[2][2]) * INV27;
    float um0 = (rm[0][0] + rm[1][0] + rm[2][0]) * INV27;
    float um1 = (rm[0][1] + rm[1][1] + rm[2][1]) * INV27;
    float um2 = (rm[0][2] + rm[1][2] + rm[2][2]) * INV27;
    float dF0 = cf0 - uf0, dF1 = cf1 - uf1, dF2 = cf2 - uf2;
    float dM0 = cm0 - um0, dM1 = cm1 - um1, dM2 = cm2 - um2;
    float3 rc = xrowsum(dF0 * dM0, dF1 * dM1, dF2 * dM2, t);
    float3 rq = xrowsum(dF0 * dF0, dF1 * dF1, dF2 * dF2, t);
    float3 rr = xrowsum(dM0 * dM0, dM1 * dM1, dM2 * dM2, t);
    *(float3*)&P[0][tt][x] = rc;
    *(float3*)&P[1][tt][x] = rq;
    *(float3*)&P[2][tt][x] = rr;
}

// read 3 PRS rows (y-window) into pn[9]
__device__ __forceinline__ void prs_read(const float P[3][NPR][DIM],
                                         int tm, int tc, int tp, int x, float pn[9]) {
#pragma unroll
    for (int q = 0; q < 3; ++q) {
        float3 u0 = *(const float3*)&P[q][tm][x];
        float3 u1 = *(const float3*)&P[q][tc][x];
        float3 u2 = *(const float3*)&P[q][tp][x];
        pn[q * 3 + 0] = u0.x + u1.x + u2.x;
        pn[q * 3 + 1] = u0.y + u1.y + u2.y;
        pn[q * 3 + 2] = u0.z + u1.z + u2.z;
    }
}

// z-window (replicate: PS(-1):=PS(0), PS(191+1):=PS(191)) -> z-score sum
__device__ __forceinline__ float zwindow(const float pm[9], const float pc[9],
                                         const float pn[9], int zo) {
    float a = 0.f;
#pragma unroll
    for (int j = 0; j < 3; ++j) {
        float a0 = (zo == 0) ? pc[j]     : pm[j];
        float a1 = (zo == 0) ? pc[3 + j] : pm[3 + j];
        float a2 = (zo == 0) ? pc[6 + j] : pm[6 + j];
        float c0 = (zo == DIM - 1) ? pc[j]     : pn[j];
        float c1 = (zo == DIM - 1) ? pc[3 + j] : pn[3 + j];
        float c2 = (zo == DIM - 1) ? pc[6 + j] : pn[6 + j];
        float cross = a0 + pc[j]     + c0;
        float vF    = a1 + pc[3 + j] + c1;
        float vM    = a2 + pc[6 + j] + c2;
        a += cross * cross / (vF * vM + EPS);
    }
    return a;
}

// ---------------------------------------------------------------------------
// Wave-per-row fused LCC, software-pipelined, balanced tasks, 512 blocks.
//   P0: stage-1 global loads (plane zc, 2 rows/wave) + product-center loads
//       (plane zc-1) -- all issued before any dependent use
//   P1: output stage for zo = zc-3 (PRS reads + PS rings)  [LDS/reg only]
//   P2: stage-1 x-rowsums -> RS (2 rows/wave, balanced)
//   BAR1
//   P3: S2D ring pushes + products -> PRS (taskA all waves, taskB waves 0-5)
//   BAR2
// NOTE: never cast GLOBAL pointers to float3 (clang widens vec3 loads to 16B
// -> OOB fault at buffer end). LDS float3 (b96) is proven safe.
// ---------------------------------------------------------------------------
__global__ __launch_bounds__(512, 4) void lcc_fused(
    const float* __restrict__ F, const float* __restrict__ M,
    float* __restrict__ out)
{
    __shared__ float RSf[NRS][DIM];
    __shared__ float RSm[NRS][DIM];
    __shared__ float PRS[3][NPR][DIM];   // 0=cross 1=ff 2=mm
    __shared__ float wred[8];

    const int tid = threadIdx.x;
    const int w   = tid >> 6;     // wave 0..7
    const int t   = tid & 63;     // lane
    const int x   = 3 * t;

    const int y0 = blockIdx.y * TY;
    const int z0 = blockIdx.x * ZC;
    const int z1 = z0 + ZC;
    const int b  = blockIdx.z;

    const float* f = F + (size_t)b * DDD;
    const float* m = M + (size_t)b * DDD;

    // stage-1 tasks: slot s holds rowsum of row clamp(y0-2+s); wave w owns
    // slots w and w+8  -> exactly 2 per wave (balanced)
    const int row1a = iclamp(y0 - 2 + w, DIM - 1);
    const int row1b = iclamp(y0 + 6 + w, DIM - 1);

    // product tasks: slot tt holds product row clamp(y0-1+tt)
    // taskA: slots 1..8 (wave w -> w+1); taskB: waves 0-5 -> slots {9..13, 0}
    const int  tA    = w + 1;
    const int  prowA = iclamp(y0 - 1 + tA, DIM - 1);
    const bool hasB  = (w < 6);
    const int  tB    = (w < 5) ? 9 + w : 0;
    const int  prowB = iclamp(y0 - 1 + tB, DIM - 1);

    // S2D y-window RS slots (double-clamped; slot = clamp(row+dy) - y0 + 2)
    const int sAm = iclamp(prowA - 1, DIM - 1) - y0 + 2;
    const int sAc = prowA - y0 + 2;
    const int sAp = iclamp(prowA + 1, DIM - 1) - y0 + 2;
    const int sBm = iclamp(prowB - 1, DIM - 1) - y0 + 2;
    const int sBc = prowB - y0 + 2;
    const int sBp = iclamp(prowB + 1, DIM - 1) - y0 + 2;

    // outputs: out1 = row y0+w (all waves); out2 = row y0+8+w (waves 0-3)
    const int  yo1  = y0 + w;
    const int  t1m  = iclamp(yo1 - 1, DIM - 1) - y0 + 1;
    const int  t1c  = w + 1;
    const int  t1p  = iclamp(yo1 + 1, DIM - 1) - y0 + 1;
    const bool has2 = (w < 4);
    const int  yo2  = y0 + 8 + w;
    const int  t2m  = iclamp(yo2 - 1, DIM - 1) - y0 + 1;
    const int  t2c  = 9 + w;
    const int  t2p  = iclamp(yo2 + 1, DIM - 1) - y0 + 1;

    const int zpLo = (z0 - 1 > 0) ? z0 - 1 : 0;
    const int zpHi = (z1 < DIM - 1) ? z1 : DIM - 1;
    const int zcStart = (z0 - 2 > -1) ? z0 - 2 : -1;
    const int zcEnd   = z1 + 2;

    // per-wave register rings
    float rAf[3][3], rAm[3][3], rBf[3][3], rBm[3][3];
    float pm1[9], pc1[9], pn1[9], pm2[9], pc2[9], pn2[9];
#pragma unroll
    for (int i = 0; i < 3; ++i)
#pragma unroll
        for (int j = 0; j < 3; ++j) {
            rAf[i][j] = 0.f; rAm[i][j] = 0.f; rBf[i][j] = 0.f; rBm[i][j] = 0.f;
        }
#pragma unroll
    for (int i = 0; i < 9; ++i) {
        pm1[i] = 0.f; pc1[i] = 0.f; pn1[i] = 0.f;
        pm2[i] = 0.f; pc2[i] = 0.f; pn2[i] = 0.f;
    }

    float accz = 0.f;

    for (int zc = zcStart; zc <= zcEnd; ++zc) {
        const bool doLoad = (zc <= zpHi + 1);
        const int  zcl  = iclamp(zc, DIM - 1);
        const size_t zoff = (size_t)zcl * DD;
        const int  zp    = zc - 1;
        const bool liveP = (zp >= zpLo) && (zp <= zpHi);

        // ------- P0: issue ALL global loads (scalar components only) -------
        float fa0 = 0, fa1 = 0, fa2 = 0, ma0 = 0, ma1 = 0, ma2 = 0;
        float fb0 = 0, fb1 = 0, fb2 = 0, mb0 = 0, mb1 = 0, mb2 = 0;
        if (doLoad) {
            const float* fr = f + zoff + (size_t)row1a * DIM + x;
            const float* mr = m + zoff + (size_t)row1a * DIM + x;
            fa0 = fr[0]; fa1 = fr[1]; fa2 = fr[2];
            ma0 = mr[0]; ma1 = mr[1]; ma2 = mr[2];
            const float* fr2 = f + zoff + (size_t)row1b * DIM + x;
            const float* mr2 = m + zoff + (size_t)row1b * DIM + x;
            fb0 = fr2[0]; fb1 = fr2[1]; fb2 = fr2[2];
            mb0 = mr2[0]; mb1 = mr2[1]; mb2 = mr2[2];
        }
        float cfA0 = 0, cfA1 = 0, cfA2 = 0, cmA0 = 0, cmA1 = 0, cmA2 = 0;
        float cfB0 = 0, cfB1 = 0, cfB2 = 0, cmB0 = 0, cmB1 = 0, cmB2 = 0;
        if (liveP) {
            const size_t poff = (size_t)zp * DD;
            const float* fv = f + poff + (size_t)prowA * DIM + x;
            const float* mv = m + poff + (size_t)prowA * DIM + x;
            cfA0 = fv[0]; cfA1 = fv[1]; cfA2 = fv[2];
            cmA0 = mv[0]; cmA1 = mv[1]; cmA2 = mv[2];
            if (hasB) {
                const float* fv2 = f + poff + (size_t)prowB * DIM + x;
                const float* mv2 = m + poff + (size_t)prowB * DIM + x;
                cfB0 = fv2[0]; cfB1 = fv2[1]; cfB2 = fv2[2];
                cmB0 = mv2[0]; cmB1 = mv2[1]; cmB2 = mv2[2];
            }
        }

        // ------- P1: output stage for zo = zc-3 (PRS holds plane zc-2) -------
        {
            const int zq = zc - 2;
            if (zq >= zpLo) {
#pragma unroll
                for (int i = 0; i < 9; ++i) { pm1[i] = pc1[i]; pc1[i] = pn1[i]; }
                if (has2) {
#pragma unroll
                    for (int i = 0; i < 9; ++i) { pm2[i] = pc2[i]; pc2[i] = pn2[i]; }
                }
                if (zq <= zpHi) {
                    prs_read(PRS, t1m, t1c, t1p, x, pn1);
                    if (has2) prs_read(PRS, t2m, t2c, t2p, x, pn2);
                }
                const int zo = zc - 3;
                if (zo >= z0 && zo < z1) {
                    accz += zwindow(pm1, pc1, pn1, zo);
                    if (has2) accz += zwindow(pm2, pc2, pn2, zo);
                }
            }
        }

        // ------- P2: stage-1 x-rowsums -> RS (2 rows/wave) -------
        if (doLoad) {
            float3 sa = xrowsum(fa0, fa1, fa2, t);
            float3 sb = xrowsum(ma0, ma1, ma2, t);
            *(float3*)&RSf[w][x] = sa;
            *(float3*)&RSm[w][x] = sb;
            float3 sc = xrowsum(fb0, fb1, fb2, t);
            float3 sd = xrowsum(mb0, mb1, mb2, t);
            *(float3*)&RSf[8 + w][x] = sc;
            *(float3*)&RSm[8 + w][x] = sd;
        }
        __syncthreads();   // BAR1

        // ------- P3: S2D ring pushes + products -> PRS -------
        if (doLoad) {
            ringpush(rAf, RSf, sAm, sAc, sAp, x);
            ringpush(rAm, RSm, sAm, sAc, sAp, x);
            if (hasB) {
                ringpush(rBf, RSf, sBm, sBc, sBp, x);
                ringpush(rBm, RSm, sBm, sBc, sBp, x);
            }
        }
        if (liveP) {
            products(rAf, rAm, cfA0, cfA1, cfA2, cmA0, cmA1, cmA2, t, tA, x, PRS);
            if (hasB)
                products(rBf, rBm, cfB0, cfB1, cfB2, cmB0, cmB1, cmB2, t, tB, x, PRS);
        }
        __syncthreads();   // BAR2
    }

    // ---- block reduction -> output (finalize fused, f32 atomic) ----
    float s = accz;
#pragma unroll
    for (int off = 32; off > 0; off >>= 1) s += __shfl_down(s, off, 64);
    if (t == 0) wred[w] = s;
    __syncthreads();
    if (tid == 0) {
        float tot = 0.f;
#pragma unroll
        for (int i = 0; i < 8; ++i) tot += wred[i];
        atomicAdd(&out[b], tot * (-1.0f / (float)DDD));
    }
}

extern "C" void kernel_launch(void* const* d_in, const int* in_sizes, int n_in,
                              void* d_out, int out_size, void* d_ws, size_t ws_size,
                              hipStream_t stream)
{
    const float* F = (const float*)d_in[0];   // im_fixed  [2,1,192,192,192] f32
    const float* M = (const float*)d_in[1];   // im_moving
    float* out = (float*)d_out;               // [2] f32

    hipMemsetAsync(d_out, 0, (size_t)out_size * sizeof(float), stream);

    dim3 grid(DIM / ZC, DIM / TY, 2);   // 16 x 16 x 2 = 512 blocks = 2/CU exact
    lcc_fused<<<grid, 512, 0, stream>>>(F, M, out);
}

// Round 7
// 160.572 us; speedup vs baseline: 1.9650x; 1.9650x over previous
//
#include <hip/hip_runtime.h>

#define DIM 192
#define DD  (DIM * DIM)
#define DDD (DIM * DIM * DIM)
#define INV27 (1.0f / 27.0f)
#define EPS 1e-5f

#define TY 12         // output rows per block (1 per wave, 12 waves)
#define ZC 24         // output planes per block
#define NRS (TY + 4)  // 16 rowsum slots  (rows y0-2 .. y0+13, clamped)
#define NPR (TY + 2)  // 14 product slots (rows y0-1 .. y0+12, clamped)
#define NW  12        // waves per block (768 threads)

// grid = (192/ZC=8, 192/TY=16, 2) = 256 blocks x 768 thr = exactly 1 block/CU

__device__ __forceinline__ int iclamp(int v, int hi) {
    return v < 0 ? 0 : (v > hi ? hi : v);
}

// x-direction 3-tap sliding sum across the wave (lane t owns x=3t..3t+2),
// replicate at x=0 / x=191.
__device__ __forceinline__ float3 xrowsum(float v0, float v1, float v2, int t) {
    float L = __shfl(v2, t - 1); L = (t == 0)  ? v0 : L;
    float R = __shfl(v0, t + 1); R = (t == 63) ? v2 : R;
    return make_float3(L + v0 + v1, v0 + v1 + v2, v1 + v2 + R);
}

// push y-window (3 rowsum rows) into a 3-deep z-ring
__device__ __forceinline__ void ringpush(float r[3][3], const float RS[][DIM],
                                         int sm_, int sc_, int sp_, int x) {
    float3 q0 = *(const float3*)&RS[sm_][x];
    float3 q1 = *(const float3*)&RS[sc_][x];
    float3 q2 = *(const float3*)&RS[sp_][x];
    r[0][0] = r[1][0]; r[0][1] = r[1][1]; r[0][2] = r[1][2];
    r[1][0] = r[2][0]; r[1][1] = r[2][1]; r[1][2] = r[2][2];
    r[2][0] = q0.x + q1.x + q2.x;
    r[2][1] = q0.y + q1.y + q2.y;
    r[2][2] = q0.z + q1.z + q2.z;
}

// dF/dM -> 3 products -> x-rowsums -> PRS row tt
__device__ __forceinline__ void products(const float rf[3][3], const float rm[3][3],
                                         float cf0, float cf1, float cf2,
                                         float cm0, float cm1, float cm2,
                                         int t, int tt, int x,
                                         float P[3][NPR][DIM]) {
    float uf0 = (rf[0][0] + rf[1][0] + rf[2][0]) * INV27;
    float uf1 = (rf[0][1] + rf[1][1] + rf[2][1]) * INV27;
    float uf2 = (rf[0][2] + rf[1][2] + rf[2][2]) * INV27;
    float um0 = (rm[0][0] + rm[1][0] + rm[2][0]) * INV27;
    float um1 = (rm[0][1] + rm[1][1] + rm[2][1]) * INV27;
    float um2 = (rm[0][2] + rm[1][2] + rm[2][2]) * INV27;
    float dF0 = cf0 - uf0, dF1 = cf1 - uf1, dF2 = cf2 - uf2;
    float dM0 = cm0 - um0, dM1 = cm1 - um1, dM2 = cm2 - um2;
    float3 rc = xrowsum(dF0 * dM0, dF1 * dM1, dF2 * dM2, t);
    float3 rq = xrowsum(dF0 * dF0, dF1 * dF1, dF2 * dF2, t);
    float3 rr = xrowsum(dM0 * dM0, dM1 * dM1, dM2 * dM2, t);
    *(float3*)&P[0][tt][x] = rc;
    *(float3*)&P[1][tt][x] = rq;
    *(float3*)&P[2][tt][x] = rr;
}

// read 3 PRS rows (y-window) into pn[9]
__device__ __forceinline__ void prs_read(const float P[3][NPR][DIM],
                                         int tm, int tc, int tp, int x, float pn[9]) {
#pragma unroll
    for (int q = 0; q < 3; ++q) {
        float3 u0 = *(const float3*)&P[q][tm][x];
        float3 u1 = *(const float3*)&P[q][tc][x];
        float3 u2 = *(const float3*)&P[q][tp][x];
        pn[q * 3 + 0] = u0.x + u1.x + u2.x;
        pn[q * 3 + 1] = u0.y + u1.y + u2.y;
        pn[q * 3 + 2] = u0.z + u1.z + u2.z;
    }
}

// z-window (replicate: PS(-1):=PS(0), PS(192):=PS(191)) -> z-score sum
__device__ __forceinline__ float zwindow(const float pm[9], const float pc[9],
                                         const float pn[9], int zo) {
    float a = 0.f;
#pragma unroll
    for (int j = 0; j < 3; ++j) {
        float a0 = (zo == 0) ? pc[j]     : pm[j];
        float a1 = (zo == 0) ? pc[3 + j] : pm[3 + j];
        float a2 = (zo == 0) ? pc[6 + j] : pm[6 + j];
        float c0 = (zo == DIM - 1) ? pc[j]     : pn[j];
        float c1 = (zo == DIM - 1) ? pc[3 + j] : pn[3 + j];
        float c2 = (zo == DIM - 1) ? pc[6 + j] : pn[6 + j];
        float cross = a0 + pc[j]     + c0;
        float vF    = a1 + pc[3 + j] + c1;
        float vM    = a2 + pc[6 + j] + c2;
        a += cross * cross / (vF * vM + EPS);
    }
    return a;
}

// ---------------------------------------------------------------------------
// Wave-per-row fused LCC, ONE barrier per z-iteration, double-buffered LDS.
// Pipeline (iteration zc, parity pw=zc&1, pr=pw^1):
//   P0: issue global loads: product-center rows (plane zc-2) + stage-1 rows
//       (plane clamp(zc))
//   P1: output stage zo=zc-4: read PRS[pr] (products of plane zc-3) -> PS ring
//   P2: S2D ring push from RS[pr] (plane clamp(zc-1)); products for plane
//       zc-2 -> PRS[pw]
//   P3: stage-1 x-rowsums of P0 regs -> RS[pw]
//   BAR (single)
// All cross-wave reads hit buffers written before the previous barrier.
// NOTE: never cast GLOBAL pointers to float3 (clang widens vec3 loads to 16B
// -> OOB fault at buffer end). LDS float3 (b96) is proven safe.
// NOTE: no 2nd __launch_bounds__ arg (R6: "(512,4)" acted as 4 blocks/CU ->
// 64-VGPR cap -> 724 MB scratch spill traffic).
// ---------------------------------------------------------------------------
__global__ __launch_bounds__(768) void lcc_fused(
    const float* __restrict__ F, const float* __restrict__ M,
    float* __restrict__ out)
{
    __shared__ float RSf[2][NRS][DIM];
    __shared__ float RSm[2][NRS][DIM];
    __shared__ float PRS[2][3][NPR][DIM];   // 0=cross 1=ff 2=mm
    __shared__ float wred[NW];

    const int tid = threadIdx.x;
    const int w   = tid >> 6;     // wave 0..11
    const int t   = tid & 63;     // lane
    const int x   = 3 * t;

    const int y0 = blockIdx.y * TY;
    const int z0 = blockIdx.x * ZC;
    const int z1 = z0 + ZC;
    const int b  = blockIdx.z;

    const float* f = F + (size_t)b * DDD;
    const float* m = M + (size_t)b * DDD;

    // stage-1 tasks: slot s holds rowsum of row clamp(y0-2+s)
    // wave w -> slot w; waves 0-3 also slot 12+w
    const int  row1a = iclamp(y0 - 2 + w, DIM - 1);
    const bool has1b = (w < NRS - NW);                    // w < 4
    const int  row1b = iclamp(y0 - 2 + NW + w, DIM - 1);  // y0+10+w

    // product tasks: slot tt holds product row clamp(y0-1+tt)
    // taskA: wave w -> slot w+1 (rows y0+w); taskB: wave0 -> slot 0, wave1 -> slot 13
    const int  tA    = w + 1;
    const int  prowA = iclamp(y0 + w, DIM - 1);
    const bool hasB  = (w < 2);
    const int  tB    = (w == 0) ? 0 : NPR - 1;
    const int  prowB = iclamp(y0 - 1 + tB, DIM - 1);

    // S2D y-window RS slots (double-clamped; slot = clamp(row+dy) - y0 + 2)
    const int sAm = iclamp(prowA - 1, DIM - 1) - y0 + 2;
    const int sAc = prowA - y0 + 2;
    const int sAp = iclamp(prowA + 1, DIM - 1) - y0 + 2;
    const int sBm = iclamp(prowB - 1, DIM - 1) - y0 + 2;
    const int sBc = prowB - y0 + 2;
    const int sBp = iclamp(prowB + 1, DIM - 1) - y0 + 2;

    // output: wave w -> row y0+w; PRS window slots
    const int yo  = y0 + w;
    const int t1m = iclamp(yo - 1, DIM - 1) - y0 + 1;
    const int t1c = w + 1;
    const int t1p = iclamp(yo + 1, DIM - 1) - y0 + 1;

    const int zpLo = (z0 - 1 > 0) ? z0 - 1 : 0;
    const int zpHi = (z1 < DIM - 1) ? z1 : DIM - 1;
    const int zcStart = zpLo - 1;
    const int zcEnd   = z1 + 3;

    // per-wave register rings
    float rAf[3][3], rAm[3][3], rBf[3][3], rBm[3][3];
    float pm[9], pc[9], pn[9];
#pragma unroll
    for (int i = 0; i < 3; ++i)
#pragma unroll
        for (int j = 0; j < 3; ++j) {
            rAf[i][j] = 0.f; rAm[i][j] = 0.f; rBf[i][j] = 0.f; rBm[i][j] = 0.f;
        }
#pragma unroll
    for (int i = 0; i < 9; ++i) { pm[i] = 0.f; pc[i] = 0.f; pn[i] = 0.f; }

    float accz = 0.f;

    for (int zc = zcStart; zc <= zcEnd; ++zc) {
        const int  pw = zc & 1;          // write-buffer parity
        const int  pr = pw ^ 1;          // read-buffer parity (last iter)
        const bool doLoad = (zc <= zpHi + 1);
        const int  zp     = zc - 2;
        const bool liveP  = (zp >= zpLo) && (zp <= zpHi);
        const bool doPush = (zc >= zpLo) && (zc <= zpHi + 2);

        // ---------- P0: issue ALL global loads (scalar components) ----------
        float cfA0 = 0, cfA1 = 0, cfA2 = 0, cmA0 = 0, cmA1 = 0, cmA2 = 0;
        float cfB0 = 0, cfB1 = 0, cfB2 = 0, cmB0 = 0, cmB1 = 0, cmB2 = 0;
        if (liveP) {
            const size_t poff = (size_t)zp * DD;
            const float* fv = f + poff + (size_t)prowA * DIM + x;
            const float* mv = m + poff + (size_t)prowA * DIM + x;
            cfA0 = fv[0]; cfA1 = fv[1]; cfA2 = fv[2];
            cmA0 = mv[0]; cmA1 = mv[1]; cmA2 = mv[2];
            if (hasB) {
                const float* fv2 = f + poff + (size_t)prowB * DIM + x;
                const float* mv2 = m + poff + (size_t)prowB * DIM + x;
                cfB0 = fv2[0]; cfB1 = fv2[1]; cfB2 = fv2[2];
                cmB0 = mv2[0]; cmB1 = mv2[1]; cmB2 = mv2[2];
            }
        }
        float fa0 = 0, fa1 = 0, fa2 = 0, ma0 = 0, ma1 = 0, ma2 = 0;
        float fb0 = 0, fb1 = 0, fb2 = 0, mb0 = 0, mb1 = 0, mb2 = 0;
        if (doLoad) {
            const int zcl = iclamp(zc, DIM - 1);
            const size_t zoff = (size_t)zcl * DD;
            const float* fr = f + zoff + (size_t)row1a * DIM + x;
            const float* mr = m + zoff + (size_t)row1a * DIM + x;
            fa0 = fr[0]; fa1 = fr[1]; fa2 = fr[2];
            ma0 = mr[0]; ma1 = mr[1]; ma2 = mr[2];
            if (has1b) {
                const float* fr2 = f + zoff + (size_t)row1b * DIM + x;
                const float* mr2 = m + zoff + (size_t)row1b * DIM + x;
                fb0 = fr2[0]; fb1 = fr2[1]; fb2 = fr2[2];
                mb0 = mr2[0]; mb1 = mr2[1]; mb2 = mr2[2];
            }
        }

        // ---------- P1: output stage zo = zc-4 (PRS[pr] holds plane zc-3) ----------
        {
            const int zq = zc - 3;
            if (zq >= zpLo) {
#pragma unroll
                for (int i = 0; i < 9; ++i) { pm[i] = pc[i]; pc[i] = pn[i]; }
                if (zq <= zpHi)
                    prs_read(PRS[pr], t1m, t1c, t1p, x, pn);
                const int zo = zc - 4;
                if (zo >= z0 && zo < z1)
                    accz += zwindow(pm, pc, pn, zo);
            }
        }

        // ---------- P2: S2D ring pushes (plane clamp(zc-1)) + products (plane zc-2) ----------
        if (doPush) {
            ringpush(rAf, RSf[pr], sAm, sAc, sAp, x);
            ringpush(rAm, RSm[pr], sAm, sAc, sAp, x);
            if (hasB) {
                ringpush(rBf, RSf[pr], sBm, sBc, sBp, x);
                ringpush(rBm, RSm[pr], sBm, sBc, sBp, x);
            }
        }
        if (liveP) {
            products(rAf, rAm, cfA0, cfA1, cfA2, cmA0, cmA1, cmA2, t, tA, x, PRS[pw]);
            if (hasB)
                products(rBf, rBm, cfB0, cfB1, cfB2, cmB0, cmB1, cmB2, t, tB, x, PRS[pw]);
        }

        // ---------- P3: stage-1 x-rowsums -> RS[pw] ----------
        if (doLoad) {
            float3 sa = xrowsum(fa0, fa1, fa2, t);
            float3 sb = xrowsum(ma0, ma1, ma2, t);
            *(float3*)&RSf[pw][w][x] = sa;
            *(float3*)&RSm[pw][w][x] = sb;
            if (has1b) {
                float3 sc = xrowsum(fb0, fb1, fb2, t);
                float3 sd = xrowsum(mb0, mb1, mb2, t);
                *(float3*)&RSf[pw][NW + w][x] = sc;
                *(float3*)&RSm[pw][NW + w][x] = sd;
            }
        }

        __syncthreads();   // single barrier per iteration
    }

    // ---- block reduction -> output (finalize fused, f32 atomic) ----
    float s = accz;
#pragma unroll
    for (int off = 32; off > 0; off >>= 1) s += __shfl_down(s, off, 64);
    if (t == 0) wred[w] = s;
    __syncthreads();
    if (tid == 0) {
        float tot = 0.f;
#pragma unroll
        for (int i = 0; i < NW; ++i) tot += wred[i];
        atomicAdd(&out[b], tot * (-1.0f / (float)DDD));
    }
}

extern "C" void kernel_launch(void* const* d_in, const int* in_sizes, int n_in,
                              void* d_out, int out_size, void* d_ws, size_t ws_size,
                              hipStream_t stream)
{
    const float* F = (const float*)d_in[0];   // im_fixed  [2,1,192,192,192] f32
    const float* M = (const float*)d_in[1];   // im_moving
    float* out = (float*)d_out;               // [2] f32

    hipMemsetAsync(d_out, 0, (size_t)out_size * sizeof(float), stream);

    dim3 grid(DIM / ZC, DIM / TY, 2);   // 8 x 16 x 2 = 256 blocks = 1/CU exact
    lcc_fused<<<grid, 768, 0, stream>>>(F, M, out);
}